// Round 1
// baseline (491.419 us; speedup 1.0000x reference)
//
#include <hip/hip_runtime.h>

#define BB 8
#define NN 2048
#define EPS 0.01f

// One block per (b, i) row. Each block streams W[b,1,i,:] (8 KB) with float4
// loads, compares against pred[b,:] staged in LDS, and contributes one
// atomicAdd to the scalar output.
__global__ __launch_bounds__(256) void coloring_loss_kernel(
    const float* __restrict__ W,
    const float* __restrict__ pred,
    float* __restrict__ out)
{
    __shared__ float s_pred[NN];
    __shared__ float s_partial[4];  // 256 threads = 4 waves

    const int bid = blockIdx.x;
    const int b = bid >> 11;          // bid / 2048
    const int i = bid & (NN - 1);     // bid % 2048
    const int t = threadIdx.x;

    // Stage pred[b, :] (8 KB) into LDS, float4-coalesced.
    const float4* p4 = (const float4*)(pred + (size_t)b * NN);
    ((float4*)s_pred)[t]       = p4[t];
    ((float4*)s_pred)[t + 256] = p4[t + 256];
    __syncthreads();

    const float pi = s_pred[i];

    // W[b, 1, i, :] row base: b*2*N*N + N*N + i*N
    const float* wrow = W + (((size_t)b * 2 + 1) * (size_t)NN + (size_t)i) * (size_t)NN;
    const float4* w4 = (const float4*)wrow;

    int cnt = 0;
#pragma unroll
    for (int h = 0; h < 2; ++h) {
        const int idx = t + h * 256;          // float4 index within the row
        const float4 w  = w4[idx];
        const float4 pj = ((const float4*)s_pred)[idx];
        cnt += (w.x == 1.0f) && (fabsf(pi - pj.x) < EPS);
        cnt += (w.y == 1.0f) && (fabsf(pi - pj.y) < EPS);
        cnt += (w.z == 1.0f) && (fabsf(pi - pj.z) < EPS);
        cnt += (w.w == 1.0f) && (fabsf(pi - pj.w) < EPS);
    }

    // Wave (64-lane) shuffle reduction.
#pragma unroll
    for (int off = 32; off > 0; off >>= 1)
        cnt += __shfl_down(cnt, off, 64);

    const int wave = t >> 6;
    const int lane = t & 63;
    if (lane == 0) s_partial[wave] = (float)cnt;
    __syncthreads();

    if (t == 0) {
        const float s = s_partial[0] + s_partial[1] + s_partial[2] + s_partial[3];
        atomicAdd(out, s);
    }
}

extern "C" void kernel_launch(void* const* d_in, const int* in_sizes, int n_in,
                              void* d_out, int out_size, void* d_ws, size_t ws_size,
                              hipStream_t stream) {
    const float* W    = (const float*)d_in[0];  // (8, 2, 2048, 2048) f32
    const float* pred = (const float*)d_in[1];  // (8, 2048) f32
    // d_in[2] (tgt) unused by the loss.
    float* out = (float*)d_out;

    // d_out is re-poisoned to 0xAA before every timed launch; zero it first.
    hipMemsetAsync(out, 0, sizeof(float), stream);

    coloring_loss_kernel<<<BB * NN, 256, 0, stream>>>(W, pred, out);
}

// Round 2
// 327.794 us; speedup vs baseline: 1.4992x; 1.4992x over previous
//
#include <hip/hip_runtime.h>

#define BB 8
#define NN 2048
#define EPS 0.01f
#define ROWS 8          // rows of W per block
#define BLOCKS_PER_B 256  // 2048 rows / 8 rows-per-block

// 2048 blocks total (256 per batch), 256 threads each.
// Each block: stage pred[b] once, hoist this thread's 8 pred_j values to
// registers, then stream 8 W-rows (8 KB each) with fully-unrolled float4
// loads (16 loads in flight per thread). One atomicAdd per block.
__global__ __launch_bounds__(256) void coloring_loss_kernel(
    const float* __restrict__ W,
    const float* __restrict__ pred,
    float* __restrict__ out)
{
    __shared__ float s_pred[NN];
    __shared__ float s_partial[4];  // 4 waves

    const int bid  = blockIdx.x;
    const int b    = bid >> 8;               // bid / 256
    const int row0 = (bid & 255) * ROWS;     // first row this block owns
    const int t    = threadIdx.x;

    // Stage pred[b, :] (8 KB) into LDS, float4-coalesced. Done once per 8 rows.
    const float4* p4 = (const float4*)(pred + (size_t)b * NN);
    ((float4*)s_pred)[t]       = p4[t];
    ((float4*)s_pred)[t + 256] = p4[t + 256];
    __syncthreads();

    // This thread's 8 comparand pred_j values -> registers (LDS read once).
    const float4 pj0 = ((const float4*)s_pred)[t];
    const float4 pj1 = ((const float4*)s_pred)[t + 256];

    // The 8 row-anchor pred_i values (block-uniform LDS reads -> broadcast).
    float pis[ROWS];
#pragma unroll
    for (int r = 0; r < ROWS; ++r) pis[r] = s_pred[row0 + r];

    // W[b, 1, row0, :] base.
    const float* wbase = W + (((size_t)b * 2 + 1) * (size_t)NN + (size_t)row0) * (size_t)NN;

    int cnt = 0;
#pragma unroll
    for (int r = 0; r < ROWS; ++r) {
        const float4* w4 = (const float4*)(wbase + (size_t)r * NN);
        const float4 w0 = w4[t];
        const float4 w1 = w4[t + 256];
        const float pi = pis[r];
        cnt += (w0.x == 1.0f) && (fabsf(pi - pj0.x) < EPS);
        cnt += (w0.y == 1.0f) && (fabsf(pi - pj0.y) < EPS);
        cnt += (w0.z == 1.0f) && (fabsf(pi - pj0.z) < EPS);
        cnt += (w0.w == 1.0f) && (fabsf(pi - pj0.w) < EPS);
        cnt += (w1.x == 1.0f) && (fabsf(pi - pj1.x) < EPS);
        cnt += (w1.y == 1.0f) && (fabsf(pi - pj1.y) < EPS);
        cnt += (w1.z == 1.0f) && (fabsf(pi - pj1.z) < EPS);
        cnt += (w1.w == 1.0f) && (fabsf(pi - pj1.w) < EPS);
    }

    // Wave (64-lane) shuffle reduction.
#pragma unroll
    for (int off = 32; off > 0; off >>= 1)
        cnt += __shfl_down(cnt, off, 64);

    const int wave = t >> 6;
    const int lane = t & 63;
    if (lane == 0) s_partial[wave] = (float)cnt;
    __syncthreads();

    if (t == 0) {
        const float s = s_partial[0] + s_partial[1] + s_partial[2] + s_partial[3];
        atomicAdd(out, s);
    }
}

extern "C" void kernel_launch(void* const* d_in, const int* in_sizes, int n_in,
                              void* d_out, int out_size, void* d_ws, size_t ws_size,
                              hipStream_t stream) {
    const float* W    = (const float*)d_in[0];  // (8, 2, 2048, 2048) f32
    const float* pred = (const float*)d_in[1];  // (8, 2048) f32
    // d_in[2] (tgt) unused by the loss.
    float* out = (float*)d_out;

    // d_out is re-poisoned to 0xAA before every timed launch; zero it first.
    hipMemsetAsync(out, 0, sizeof(float), stream);

    coloring_loss_kernel<<<BB * BLOCKS_PER_B, 256, 0, stream>>>(W, pred, out);
}

// Round 3
// 325.709 us; speedup vs baseline: 1.5088x; 1.0064x over previous
//
#include <hip/hip_runtime.h>

#define BB 8
#define NN 2048
#define EPS 0.01f
#define ROWS 16           // rows of W per block
#define BLOCKS_PER_B 128  // 2048 / 16

// 1024 blocks (128 per batch), 256 threads. No LDS staging: each thread's two
// pred float4 comparands live in registers (L1-hit loads; pred[b] is 8 KB),
// and the 16 row-anchor pred_i are block-uniform -> scalar loads. Each thread
// streams 32 float4 of W (512 B). One atomicAdd per block.
__global__ __launch_bounds__(256) void coloring_loss_kernel(
    const float* __restrict__ W,
    const float* __restrict__ pred,
    float* __restrict__ out)
{
    __shared__ float s_partial[4];  // 4 waves

    const int bid  = blockIdx.x;
    const int b    = bid >> 7;               // bid / 128
    const int row0 = (bid & 127) * ROWS;     // first row this block owns
    const int t    = threadIdx.x;

    const float* predb = pred + (size_t)b * NN;

    // This thread's 8 comparand pred_j values -> registers (L1/L2 hits).
    const float4 pj0 = ((const float4*)predb)[t];
    const float4 pj1 = ((const float4*)predb)[t + 256];

    // Row-anchor pred_i values: block-uniform addresses -> scalar loads.
    float pis[ROWS];
#pragma unroll
    for (int r = 0; r < ROWS; ++r) pis[r] = predb[row0 + r];

    // W[b, 1, row0, :] base.
    const float* wbase = W + (((size_t)b * 2 + 1) * (size_t)NN + (size_t)row0) * (size_t)NN;

    int cnt = 0;
#pragma unroll
    for (int r = 0; r < ROWS; ++r) {
        const float4* w4 = (const float4*)(wbase + (size_t)r * NN);
        const float4 w0 = w4[t];
        const float4 w1 = w4[t + 256];
        const float pi = pis[r];
        cnt += (w0.x == 1.0f) && (fabsf(pi - pj0.x) < EPS);
        cnt += (w0.y == 1.0f) && (fabsf(pi - pj0.y) < EPS);
        cnt += (w0.z == 1.0f) && (fabsf(pi - pj0.z) < EPS);
        cnt += (w0.w == 1.0f) && (fabsf(pi - pj0.w) < EPS);
        cnt += (w1.x == 1.0f) && (fabsf(pi - pj1.x) < EPS);
        cnt += (w1.y == 1.0f) && (fabsf(pi - pj1.y) < EPS);
        cnt += (w1.z == 1.0f) && (fabsf(pi - pj1.z) < EPS);
        cnt += (w1.w == 1.0f) && (fabsf(pi - pj1.w) < EPS);
    }

    // Wave (64-lane) shuffle reduction.
#pragma unroll
    for (int off = 32; off > 0; off >>= 1)
        cnt += __shfl_down(cnt, off, 64);

    const int wave = t >> 6;
    const int lane = t & 63;
    if (lane == 0) s_partial[wave] = (float)cnt;
    __syncthreads();

    if (t == 0) {
        const float s = s_partial[0] + s_partial[1] + s_partial[2] + s_partial[3];
        atomicAdd(out, s);
    }
}

extern "C" void kernel_launch(void* const* d_in, const int* in_sizes, int n_in,
                              void* d_out, int out_size, void* d_ws, size_t ws_size,
                              hipStream_t stream) {
    const float* W    = (const float*)d_in[0];  // (8, 2, 2048, 2048) f32
    const float* pred = (const float*)d_in[1];  // (8, 2048) f32
    // d_in[2] (tgt) unused by the loss.
    float* out = (float*)d_out;

    // d_out is re-poisoned to 0xAA before every timed launch; zero it first.
    hipMemsetAsync(out, 0, sizeof(float), stream);

    coloring_loss_kernel<<<BB * BLOCKS_PER_B, 256, 0, stream>>>(W, pred, out);
}

// Round 4
// 322.162 us; speedup vs baseline: 1.5254x; 1.0110x over previous
//
#include <hip/hip_runtime.h>

#define BB 8
#define NN 2048
#define EPS 0.01f
#define ROWS 8            // rows of W per block
#define BLOCKS_PER_B 256  // 2048 / 8
#define NBLK (BB * BLOCKS_PER_B)  // 2048 blocks

// Stage 1: 2048 blocks (256/batch), 256 threads. Register-only pred
// comparands, 16 float4 W loads per thread, wave shuffle reduce, one plain
// float store per block into d_ws (no same-address atomics anywhere).
__global__ __launch_bounds__(256, 4) void coloring_loss_stage1(
    const float* __restrict__ W,
    const float* __restrict__ pred,
    float* __restrict__ partial)
{
    __shared__ float s_partial[4];  // 4 waves

    const int bid  = blockIdx.x;
    const int b    = bid >> 8;               // bid / 256
    const int row0 = (bid & 255) * ROWS;     // first row this block owns
    const int t    = threadIdx.x;

    const float* predb = pred + (size_t)b * NN;

    // This thread's 8 comparand pred_j values -> registers (L1/L2 hits).
    const float4 pj0 = ((const float4*)predb)[t];
    const float4 pj1 = ((const float4*)predb)[t + 256];

    // Row-anchor pred_i values: block-uniform addresses -> scalar loads.
    float pis[ROWS];
#pragma unroll
    for (int r = 0; r < ROWS; ++r) pis[r] = predb[row0 + r];

    // W[b, 1, row0, :] base.
    const float* wbase = W + (((size_t)b * 2 + 1) * (size_t)NN + (size_t)row0) * (size_t)NN;

    int cnt = 0;
#pragma unroll
    for (int r = 0; r < ROWS; ++r) {
        const float4* w4 = (const float4*)(wbase + (size_t)r * NN);
        const float4 w0 = w4[t];
        const float4 w1 = w4[t + 256];
        const float pi = pis[r];
        cnt += (w0.x == 1.0f) && (fabsf(pi - pj0.x) < EPS);
        cnt += (w0.y == 1.0f) && (fabsf(pi - pj0.y) < EPS);
        cnt += (w0.z == 1.0f) && (fabsf(pi - pj0.z) < EPS);
        cnt += (w0.w == 1.0f) && (fabsf(pi - pj0.w) < EPS);
        cnt += (w1.x == 1.0f) && (fabsf(pi - pj1.x) < EPS);
        cnt += (w1.y == 1.0f) && (fabsf(pi - pj1.y) < EPS);
        cnt += (w1.z == 1.0f) && (fabsf(pi - pj1.z) < EPS);
        cnt += (w1.w == 1.0f) && (fabsf(pi - pj1.w) < EPS);
    }

    // Wave (64-lane) shuffle reduction.
#pragma unroll
    for (int off = 32; off > 0; off >>= 1)
        cnt += __shfl_down(cnt, off, 64);

    const int wave = t >> 6;
    const int lane = t & 63;
    if (lane == 0) s_partial[wave] = (float)cnt;
    __syncthreads();

    if (t == 0) {
        partial[bid] = s_partial[0] + s_partial[1] + s_partial[2] + s_partial[3];
    }
}

// Stage 2: one block reduces the 2048 partials -> out[0]. Overwrites out
// unconditionally (d_out is poisoned 0xAA before every timed launch).
__global__ __launch_bounds__(256) void coloring_loss_stage2(
    const float* __restrict__ partial,
    float* __restrict__ out)
{
    __shared__ float s_partial[4];
    const int t = threadIdx.x;

    float s = 0.0f;
#pragma unroll
    for (int k = 0; k < NBLK / 256; ++k)
        s += partial[t + k * 256];

#pragma unroll
    for (int off = 32; off > 0; off >>= 1)
        s += __shfl_down(s, off, 64);

    const int wave = t >> 6;
    const int lane = t & 63;
    if (lane == 0) s_partial[wave] = s;
    __syncthreads();

    if (t == 0)
        out[0] = s_partial[0] + s_partial[1] + s_partial[2] + s_partial[3];
}

extern "C" void kernel_launch(void* const* d_in, const int* in_sizes, int n_in,
                              void* d_out, int out_size, void* d_ws, size_t ws_size,
                              hipStream_t stream) {
    const float* W    = (const float*)d_in[0];  // (8, 2, 2048, 2048) f32
    const float* pred = (const float*)d_in[1];  // (8, 2048) f32
    // d_in[2] (tgt) unused by the loss.
    float* out     = (float*)d_out;
    float* partial = (float*)d_ws;  // 2048 floats of scratch

    coloring_loss_stage1<<<NBLK, 256, 0, stream>>>(W, pred, partial);
    coloring_loss_stage2<<<1, 256, 0, stream>>>(partial, out);
}